// Round 1
// baseline (599.430 us; speedup 1.0000x reference)
//
#include <hip/hip_runtime.h>

#define HEADS 4
#define BB    2
#define CKD   64
#define CH    16      // CK/HEADS
#define K2    32      // 2*CH (mk3, mk interleaved)
#define HWD   1024
#define THW   8192
#define CVD   512
#define CVH   128
#define MT    32      // m per block
#define NC    8       // n-chunks
#define NR    1024    // THW/NC, n per block
#define NSUB  16
#define SUBS  64      // NR/NSUB
#define MOP   516     // padded moS row stride (floats)

// ---------------- init: zero mem half, copy qv half ----------------
__global__ __launch_bounds__(256)
void mr_init(const float* __restrict__ qv, float* __restrict__ out) {
    int idx = blockIdx.x * 256 + threadIdx.x;   // float4 index; 524288 total
    int b   = idx >> 18;                        // 262144 f4 per batch
    int r   = idx & 262143;
    int ch  = r >> 8;                           // channel (1024 f = 256 f4)
    float4 v = make_float4(0.f, 0.f, 0.f, 0.f);
    if (ch >= CVD) {
        v = ((const float4*)qv)[(b << 17) + ((ch - CVD) << 8) + (r & 255)];
    }
    ((float4*)out)[idx] = v;
}

// ---------------- fused main kernel ----------------
__global__ __launch_bounds__(256, 2)
void mr_main(const float* __restrict__ mk, const float* __restrict__ qk,
             const float* __restrict__ ms, const float* __restrict__ qe,
             const float* __restrict__ mv, float* __restrict__ out)
{
    __shared__ __align__(16) float mkS[HEADS][NSUB][K2]; // [h][nn][k] k-contig
    __shared__ __align__(16) float sS[NSUB][HEADS][MT];  // sim -> aff in place
    __shared__ __align__(16) float moS[NSUB][MOP];       // [nn][cv] (+pad)
    __shared__ __align__(16) float msS[NR];

    const int t  = threadIdx.x;
    const int m0 = blockIdx.x * MT;
    const int n0 = blockIdx.y * NR;
    const int b  = blockIdx.z;

    // phase-1 roles: (m, h, nn-half)
    const int pm  = t & 31;
    const int ph  = (t >> 5) & 3;
    const int pnh = t >> 7;
    // phase-3 roles: 32 cv-groups x 8 m-groups
    const int rm  = (t & 7) * 4;
    const int rcv = (t >> 3) * 16;
    const int rh  = t >> 6;           // = rcv / CVH

    // stage ms for the whole n-range (1024 floats)
    {
        const float4* msp = (const float4*)(ms + b * THW + n0);
        ((float4*)msS)[t] = msp[t];
    }

    // per-(h,m) similarity weights + bias, persistent in registers
    float wreg[K2];
    float breg = 0.f;
    {
        const float* qkp = qk + b * CKD * HWD + (ph * CH) * HWD + m0 + pm;
        const float* qep = qe + b * CKD * HWD + (ph * CH) * HWD + m0 + pm;
#pragma unroll
        for (int c = 0; c < CH; ++c) {
            float qkv = qkp[c * HWD];
            float qev = qep[c * HWD];
            wreg[2 * c]     = -qev;              // coeff of mk^3
            wreg[2 * c + 1] = 2.f * qkv * qev;   // coeff of mk
            breg -= qev * qkv * qkv * qkv;       // -sum qe*qk^3
        }
    }

    float acc[16][4];
#pragma unroll
    for (int i = 0; i < 16; ++i)
#pragma unroll
        for (int j = 0; j < 4; ++j) acc[i][j] = 0.f;

    const float* mvb = mv + (size_t)b * CVD * THW + n0;
    const float* mkb = mk + (size_t)b * CKD * THW + n0;

    for (int s = 0; s < SUBS; ++s) {
        const int ns = s * NSUB;

        // ---- stage mk (+cube): 64 ck x 16 nn ----
        {
            const int ck = t >> 2, nn4 = t & 3;
            float4 v = *(const float4*)(mkb + ck * THW + ns + nn4 * 4);
            const int h = ck >> 4, c = ck & 15;
            float vs[4] = {v.x, v.y, v.z, v.w};
#pragma unroll
            for (int j = 0; j < 4; ++j) {
                float x = vs[j];
                mkS[h][nn4 * 4 + j][2 * c]     = x * x * x;
                mkS[h][nn4 * 4 + j][2 * c + 1] = x;
            }
        }
        // ---- stage mo: 512 cv x 16 nn, coalesced f4 over nn ----
        {
#pragma unroll
            for (int i = 0; i < 8; ++i) {
                int q   = t + 256 * i;      // [0,2048)
                int cv  = q >> 2;
                int nn4 = q & 3;
                float4 v = *(const float4*)(mvb + cv * THW + ns + nn4 * 4);
                moS[nn4 * 4 + 0][cv] = v.x;
                moS[nn4 * 4 + 1][cv] = v.y;
                moS[nn4 * 4 + 2][cv] = v.z;
                moS[nn4 * 4 + 3][cv] = v.w;
            }
        }
        __syncthreads();

        // ---- P1: similarity (weights in regs, mk broadcast from LDS) ----
        {
#pragma unroll
            for (int u = 0; u < 8; ++u) {
                int nn = pnh * 8 + u;
                const float4* mk4 = (const float4*)(&mkS[ph][nn][0]);
                float dot = 0.f;
#pragma unroll
                for (int k4 = 0; k4 < 8; ++k4) {
                    float4 v = mk4[k4];
                    dot = fmaf(v.x, wreg[4 * k4 + 0], dot);
                    dot = fmaf(v.y, wreg[4 * k4 + 1], dot);
                    dot = fmaf(v.z, wreg[4 * k4 + 2], dot);
                    dot = fmaf(v.w, wreg[4 * k4 + 3], dot);
                }
                sS[nn][ph][pm] = (dot + breg) * msS[ns + nn] * 0.125f;
            }
        }
        __syncthreads();

        // ---- P2: softmax over the 4 heads, in place ----
        {
#pragma unroll
            for (int u = 0; u < 2; ++u) {
                int p  = t + 256 * u;       // [0,512)
                int nn = p >> 5, m = p & 31;
                float s0 = sS[nn][0][m], s1 = sS[nn][1][m];
                float s2 = sS[nn][2][m], s3 = sS[nn][3][m];
                float mx = fmaxf(fmaxf(s0, s1), fmaxf(s2, s3));
                float e0 = __expf(s0 - mx), e1 = __expf(s1 - mx);
                float e2 = __expf(s2 - mx), e3 = __expf(s3 - mx);
                float r = 1.f / (e0 + e1 + e2 + e3);
                sS[nn][0][m] = e0 * r;
                sS[nn][1][m] = e1 * r;
                sS[nn][2][m] = e2 * r;
                sS[nn][3][m] = e3 * r;
            }
        }
        __syncthreads();

        // ---- P3: readout, 16cv x 4m register tile ----
        {
#pragma unroll 4
            for (int nn = 0; nn < NSUB; ++nn) {
                float4 af = *(const float4*)(&sS[nn][rh][rm]);
                float4 ma = *(const float4*)(&moS[nn][rcv + 0]);
                float4 mb = *(const float4*)(&moS[nn][rcv + 4]);
                float4 mc = *(const float4*)(&moS[nn][rcv + 8]);
                float4 md = *(const float4*)(&moS[nn][rcv + 12]);
                float av[4]   = {af.x, af.y, af.z, af.w};
                float mo16[16] = {ma.x, ma.y, ma.z, ma.w, mb.x, mb.y, mb.z, mb.w,
                                  mc.x, mc.y, mc.z, mc.w, md.x, md.y, md.z, md.w};
#pragma unroll
                for (int i = 0; i < 16; ++i)
#pragma unroll
                    for (int j = 0; j < 4; ++j)
                        acc[i][j] = fmaf(mo16[i], av[j], acc[i][j]);
            }
        }
        __syncthreads();
    }

    // ---- epilogue: accumulate n-chunk partials ----
    float* ob = out + (size_t)b * (2 * CVD * HWD) + (size_t)rcv * HWD + m0 + rm;
#pragma unroll
    for (int i = 0; i < 16; ++i)
#pragma unroll
        for (int j = 0; j < 4; ++j)
#if defined(__HIP_PLATFORM_AMD__)
            unsafeAtomicAdd(ob + i * HWD + j, acc[i][j]);
#else
            atomicAdd(ob + i * HWD + j, acc[i][j]);
#endif
}

extern "C" void kernel_launch(void* const* d_in, const int* in_sizes, int n_in,
                              void* d_out, int out_size, void* d_ws, size_t ws_size,
                              hipStream_t stream) {
    (void)in_sizes; (void)n_in; (void)out_size; (void)d_ws; (void)ws_size;
    const float* mk = (const float*)d_in[0];
    const float* qk = (const float*)d_in[1];
    const float* ms = (const float*)d_in[2];
    const float* qe = (const float*)d_in[3];
    const float* mv = (const float*)d_in[4];
    const float* qv = (const float*)d_in[5];
    float* out = (float*)d_out;

    mr_init<<<2048, 256, 0, stream>>>(qv, out);
    mr_main<<<dim3(32, NC, BB), 256, 0, stream>>>(mk, qk, ms, qe, mv, out);
}

// Round 2
// 402.118 us; speedup vs baseline: 1.4907x; 1.4907x over previous
//
#include <hip/hip_runtime.h>

typedef float f4 __attribute__((ext_vector_type(4)));
typedef short s4 __attribute__((ext_vector_type(4)));
typedef short s8 __attribute__((ext_vector_type(8)));

#define HEADS 4
#define BB    2
#define CKD   64
#define CH    16
#define HWD   1024
#define THW   8192
#define CVD   512
#define MT    64      // m-columns per block
#define NC    8       // n-chunks (grid.y)
#define NRANGE 1024   // n per block
#define NSUB  32      // n per sub-chunk == MFMA K
#define SUBS  32      // NRANGE/NSUB
#define MOP   36      // padded row length (shorts) for moS/affS
#define SSP   36      // padded row length (floats) for sS/mkS

__device__ __forceinline__ unsigned short f2bf(float x) {
    unsigned u = __builtin_bit_cast(unsigned, x);
    u += 0x7fffu + ((u >> 16) & 1u);          // RNE
    return (unsigned short)(u >> 16);
}
__device__ __forceinline__ float bf2f(unsigned short b) {
    unsigned u = ((unsigned)b) << 16;
    return __builtin_bit_cast(float, u);
}

// ---------------- init: zero mem half, copy qv half ----------------
__global__ __launch_bounds__(256)
void mr_init(const float* __restrict__ qv, float* __restrict__ out) {
    int idx = blockIdx.x * 256 + threadIdx.x;   // float4 index; 524288 total
    int b   = idx >> 18;
    int r   = idx & 262143;
    int ch  = r >> 8;
    float4 v = make_float4(0.f, 0.f, 0.f, 0.f);
    if (ch >= CVD) {
        v = ((const float4*)qv)[(b << 17) + ((ch - CVD) << 8) + (r & 255)];
    }
    ((float4*)out)[idx] = v;
}

// ---------------- fused main kernel ----------------
__global__ __launch_bounds__(512, 2)
void mr_main(const float* __restrict__ mk, const float* __restrict__ qk,
             const float* __restrict__ ms, const float* __restrict__ qe,
             const float* __restrict__ mv, float* __restrict__ out)
{
    __shared__ __align__(16) float msS[NRANGE];                 //  4 KB
    __shared__ __align__(16) float sS[HEADS][MT][SSP];          // 36 KB  sim (quad-XOR swizzled)
    __shared__ __align__(16) short moH[HEADS][128][MOP];        // 36 KB  mo bf16 hi
    __shared__ __align__(16) short moL[HEADS][128][MOP];        // 36 KB  mo bf16 lo
    __shared__ __align__(16) char  ovl[HEADS * MT * MOP * 2 * 2]; // 36 KB mkS/affS overlay

    float (*mkS)[32][SSP] = (float(*)[32][SSP])ovl;                   // [h][k][nn]
    short (*affS)[HEADS][MT][MOP] = (short(*)[HEADS][MT][MOP])ovl;    // [hi/lo][h][m][nn]

    const int t  = threadIdx.x;
    const int m0 = blockIdx.x * MT;
    const int n0 = blockIdx.y * NRANGE;
    const int b  = blockIdx.z;

    // stage ms for the whole n-range
    if (t < 256) ((f4*)msS)[t] = ((const f4*)(ms + b * THW + n0))[t];

    // ---- P1 roles ----
    const int pm  = t & 63;
    const int ph  = (t >> 6) & 3;
    const int pnh = t >> 8;

    // per-(h,m) similarity weights + bias, resident in registers
    float w[32];
    float breg = 0.f;
    {
        const float* qkp = qk + (b * CKD + ph * CH) * HWD + m0 + pm;
        const float* qep = qe + (b * CKD + ph * CH) * HWD + m0 + pm;
#pragma unroll
        for (int c = 0; c < CH; ++c) {
            float kv = qkp[c * HWD];
            float ev = qep[c * HWD];
            w[2 * c]     = -ev;              // coeff of mk^3
            w[2 * c + 1] = 2.f * kv * ev;    // coeff of mk
            breg        -= ev * kv * kv * kv;
        }
    }

    // ---- P3 roles: wave = (h, m-half); lane = (row-in-tile, k-group) ----
    const int wv  = t >> 6;
    const int ln  = t & 63;
    const int wh  = wv & 3;
    const int wmh = wv >> 2;
    const int lr  = ln & 15;
    const int lg  = ln >> 4;

    f4 acc[8][2];
#pragma unroll
    for (int i = 0; i < 8; ++i) {
        acc[i][0] = f4{0.f, 0.f, 0.f, 0.f};
        acc[i][1] = f4{0.f, 0.f, 0.f, 0.f};
    }

    const float* mvb = mv + (size_t)b * CVD * THW + n0;
    const float* mkb = mk + (size_t)b * CKD * THW + n0;

    for (int s = 0; s < SUBS; ++s) {
        const int ns = s * NSUB;

        // ---- stage mk (+cube), fp32: 64 ck x 32 nn ----
        {
            const int ck = t >> 3, j = t & 7;
            f4 v  = *(const f4*)(mkb + ck * THW + ns + j * 4);
            f4 v3 = v * v * v;
            const int h = ck >> 4, c = ck & 15;
            *(f4*)&mkS[h][2 * c    ][j * 4] = v3;
            *(f4*)&mkS[h][2 * c + 1][j * 4] = v;
        }
        // ---- stage mo -> bf16 hi/lo: 512 cv x 32 nn ----
#pragma unroll
        for (int i = 0; i < 8; ++i) {
            const int idx = t + 512 * i;
            const int cv = idx >> 3, j = idx & 7;
            f4 v = *(const f4*)(mvb + cv * THW + ns + j * 4);
            s4 hi, lo;
#pragma unroll
            for (int e = 0; e < 4; ++e) {
                unsigned short hb = f2bf(v[e]);
                hi[e] = (short)hb;
                lo[e] = (short)f2bf(v[e] - bf2f(hb));
            }
            const int h = cv >> 7, cl = cv & 127;
            *(s4*)&moH[h][cl][j * 4] = hi;
            *(s4*)&moL[h][cl][j * 4] = lo;
        }
        __syncthreads();

        // ---- P1: similarity (fp32 VALU; mk broadcast from LDS, w in regs) ----
        {
            f4 a0 = f4{0.f,0.f,0.f,0.f}, a1 = f4{0.f,0.f,0.f,0.f};
            f4 a2 = f4{0.f,0.f,0.f,0.f}, a3 = f4{0.f,0.f,0.f,0.f};
            const float* mkrow = &mkS[ph][0][pnh * 16];
#pragma unroll
            for (int k = 0; k < 32; ++k) {
                const f4* r = (const f4*)(mkrow + k * SSP);
                const float wk = w[k];
                a0 += wk * r[0]; a1 += wk * r[1]; a2 += wk * r[2]; a3 += wk * r[3];
            }
            const int sw = (pm >> 3) & 3;
            float* srow = &sS[ph][pm][0];
            f4 sims[4] = {a0, a1, a2, a3};
#pragma unroll
            for (int i = 0; i < 4; ++i) {
                const int ql = pnh * 4 + i;
                f4 v = sims[i] + breg;
                *(f4*)&srow[(ql ^ sw) * 4] = v;     // quad-XOR: kills stride-36 8-way conflict
            }
        }
        __syncthreads();

        // ---- P2: softmax over heads + bf16 hi/lo into B-fragment layout ----
        {
            const int qm = t & 63, qq = t >> 6;
            const int pq = qq ^ ((qm >> 3) & 3);
            f4 sv[HEADS];
#pragma unroll
            for (int h = 0; h < HEADS; ++h)
                sv[h] = *(const f4*)&sS[h][qm][pq * 4];
            f4 msv = *(const f4*)&msS[ns + qq * 4];
            float af[HEADS][4];
#pragma unroll
            for (int e = 0; e < 4; ++e) {
                const float sc = msv[e] * 0.125f;
                float x0 = sv[0][e] * sc, x1 = sv[1][e] * sc;
                float x2 = sv[2][e] * sc, x3 = sv[3][e] * sc;
                float mx = fmaxf(fmaxf(x0, x1), fmaxf(x2, x3));
                float e0 = __expf(x0 - mx), e1 = __expf(x1 - mx);
                float e2 = __expf(x2 - mx), e3 = __expf(x3 - mx);
                float r = 1.f / (e0 + e1 + e2 + e3);
                af[0][e] = e0 * r; af[1][e] = e1 * r;
                af[2][e] = e2 * r; af[3][e] = e3 * r;
            }
#pragma unroll
            for (int h = 0; h < HEADS; ++h) {
                s4 hi, lo;
#pragma unroll
                for (int e = 0; e < 4; ++e) {
                    unsigned short hb = f2bf(af[h][e]);
                    hi[e] = (short)hb;
                    lo[e] = (short)f2bf(af[h][e] - bf2f(hb));
                }
                *(s4*)&affS[0][h][qm][qq * 4] = hi;
                *(s4*)&affS[1][h][qm][qq * 4] = lo;
            }
        }
        __syncthreads();

        // ---- P3: readout via MFMA, hi/lo split (3 products ~ fp32 accuracy) ----
        {
            s8 bH[2], bL[2];
#pragma unroll
            for (int mt = 0; mt < 2; ++mt) {
                const short* bp0 = &affS[0][wh][wmh * 32 + mt * 16 + lr][lg * 8];
                const short* bp1 = &affS[1][wh][wmh * 32 + mt * 16 + lr][lg * 8];
                bH[mt] = __builtin_shufflevector(*(const s4*)bp0, *(const s4*)(bp0 + 4),
                                                 0,1,2,3,4,5,6,7);
                bL[mt] = __builtin_shufflevector(*(const s4*)bp1, *(const s4*)(bp1 + 4),
                                                 0,1,2,3,4,5,6,7);
            }
#pragma unroll
            for (int cv = 0; cv < 8; ++cv) {
                const short* ap0 = &moH[wh][cv * 16 + lr][lg * 8];
                const short* ap1 = &moL[wh][cv * 16 + lr][lg * 8];
                s8 aH = __builtin_shufflevector(*(const s4*)ap0, *(const s4*)(ap0 + 4),
                                                0,1,2,3,4,5,6,7);
                s8 aL = __builtin_shufflevector(*(const s4*)ap1, *(const s4*)(ap1 + 4),
                                                0,1,2,3,4,5,6,7);
#pragma unroll
                for (int mt = 0; mt < 2; ++mt) {
                    acc[cv][mt] = __builtin_amdgcn_mfma_f32_16x16x32_bf16(aH, bH[mt], acc[cv][mt], 0, 0, 0);
                    acc[cv][mt] = __builtin_amdgcn_mfma_f32_16x16x32_bf16(aL, bH[mt], acc[cv][mt], 0, 0, 0);
                    acc[cv][mt] = __builtin_amdgcn_mfma_f32_16x16x32_bf16(aH, bL[mt], acc[cv][mt], 0, 0, 0);
                }
            }
        }
        __syncthreads();
    }

    // ---- epilogue: combine n-chunk partials via hw fp32 atomics ----
    float* ob = out + (size_t)b * (2 * CVD * HWD);
#pragma unroll
    for (int cv = 0; cv < 8; ++cv)
#pragma unroll
        for (int mt = 0; mt < 2; ++mt)
#pragma unroll
            for (int r = 0; r < 4; ++r) {
                const int cvg = wh * 128 + cv * 16 + lg * 4 + r;  // D row = (lane>>4)*4 + reg
                const int mg  = m0 + wmh * 32 + mt * 16 + lr;     // D col = lane&15
#if defined(__HIP_PLATFORM_AMD__)
                unsafeAtomicAdd(ob + (size_t)cvg * HWD + mg, acc[cv][mt][r]);
#else
                atomicAdd(ob + (size_t)cvg * HWD + mg, acc[cv][mt][r]);
#endif
            }
}

extern "C" void kernel_launch(void* const* d_in, const int* in_sizes, int n_in,
                              void* d_out, int out_size, void* d_ws, size_t ws_size,
                              hipStream_t stream) {
    (void)in_sizes; (void)n_in; (void)out_size; (void)d_ws; (void)ws_size;
    const float* mk = (const float*)d_in[0];
    const float* qk = (const float*)d_in[1];
    const float* ms = (const float*)d_in[2];
    const float* qe = (const float*)d_in[3];
    const float* mv = (const float*)d_in[4];
    const float* qv = (const float*)d_in[5];
    float* out = (float*)d_out;

    mr_init<<<2048, 256, 0, stream>>>(qv, out);
    mr_main<<<dim3(1024 / MT, NC, BB), 512, 0, stream>>>(mk, qk, ms, qe, mv, out);
}

// Round 4
// 288.771 us; speedup vs baseline: 2.0758x; 1.3925x over previous
//
#include <hip/hip_runtime.h>

typedef float f4 __attribute__((ext_vector_type(4)));
typedef short s4 __attribute__((ext_vector_type(4)));
typedef short s8 __attribute__((ext_vector_type(8)));

#define HWD    1024
#define THW    8192
#define CVD    512
#define MT     64     // m per block
#define NC     8      // n-chunks
#define NRANGE 1024   // n per block
#define NSUB   32     // n per iter = MFMA K
#define SUBS   32
#define AFP    36     // padded row (shorts) for w/aff tiles

#define MFMA16 __builtin_amdgcn_mfma_f32_16x16x32_bf16

__device__ __forceinline__ unsigned short f2bf(float x) {
    unsigned u = __builtin_bit_cast(unsigned, x);
    u += 0x7fffu + ((u >> 16) & 1u);          // RNE
    return (unsigned short)(u >> 16);
}
__device__ __forceinline__ float bf2f(unsigned short b) {
    unsigned u = ((unsigned)b) << 16;
    return __builtin_bit_cast(float, u);
}

// ---------------- init: zero mem half, copy qv half ----------------
__global__ __launch_bounds__(256)
void mr_init(const float* __restrict__ qv, float* __restrict__ out) {
    int idx = blockIdx.x * 256 + threadIdx.x;   // f4 idx; 524288 total
    int b   = idx >> 18;
    int r   = idx & 262143;
    int ch  = r >> 8;
    float4 v = make_float4(0.f, 0.f, 0.f, 0.f);
    if (ch >= CVD) {
        v = ((const float4*)qv)[(b << 17) + ((ch - CVD) << 8) + (r & 255)];
    }
    ((float4*)out)[idx] = v;
}

// ---------------- prep: mv fp32 -> bf16 hi/lo ----------------
__global__ __launch_bounds__(256)
void prep_mv(const float* __restrict__ mv, short* __restrict__ mvH, short* __restrict__ mvL) {
    int i = blockIdx.x * 256 + threadIdx.x;     // f4 idx; 2,097,152 total
    f4 v = ((const f4*)mv)[i];
    s4 hi, lo;
#pragma unroll
    for (int e = 0; e < 4; ++e) {
        unsigned short h = f2bf(v[e]);
        hi[e] = (short)h;
        lo[e] = (short)f2bf(v[e] - bf2f(h));
    }
    ((s4*)mvH)[i] = hi;
    ((s4*)mvL)[i] = lo;
}

// ---------------- prep: mk -> feature rows (mk^3, mk) bf16 hi/lo ----------------
// feat[b][h][n][32]: [2c]=mk^3, [2c+1]=mk   (k contiguous, 64B rows)
__global__ __launch_bounds__(256)
void prep_feat(const float* __restrict__ mk, short* __restrict__ ftH, short* __restrict__ ftL) {
    __shared__ float mkT[16][260];
    const int bid = blockIdx.x;                  // 256 = b2 * h4 * chunk32
    const int chunk = bid & 31, h = (bid >> 5) & 3, b = bid >> 7;
    const int t = threadIdx.x;
    const float* src = mk + (size_t)(b * 64 + h * 16) * THW + chunk * 256;
#pragma unroll
    for (int i = 0; i < 4; ++i) {
        int q = t + 256 * i;                     // 1024 f4 = 16c x 64
        int c = q >> 6, j = q & 63;
        *(f4*)&mkT[c][j * 4] = *(const f4*)(src + (size_t)c * THW + j * 4);
    }
    __syncthreads();
    unsigned uH[16], uL[16];
#pragma unroll
    for (int c = 0; c < 16; ++c) {
        float x  = mkT[c][t];
        float x3 = x * x * x;
        unsigned short h3 = f2bf(x3), h1 = f2bf(x);
        unsigned short l3 = f2bf(x3 - bf2f(h3)), l1 = f2bf(x - bf2f(h1));
        uH[c] = (unsigned)h3 | ((unsigned)h1 << 16);
        uL[c] = (unsigned)l3 | ((unsigned)l1 << 16);
    }
    size_t row = ((size_t)(b * 4 + h) * THW + chunk * 256 + t) * 32;
    uint4* dH = (uint4*)(ftH + row);
    uint4* dL = (uint4*)(ftL + row);
#pragma unroll
    for (int k = 0; k < 4; ++k) {
        dH[k] = make_uint4(uH[4*k], uH[4*k+1], uH[4*k+2], uH[4*k+3]);
        dL[k] = make_uint4(uL[4*k], uL[4*k+1], uL[4*k+2], uL[4*k+3]);
    }
}

// ---------------- fused main kernel ----------------
__global__ __launch_bounds__(512, 4)
void mr_main(const float* __restrict__ qk, const float* __restrict__ qe,
             const float* __restrict__ ms,
             const short* __restrict__ mvH, const short* __restrict__ mvL,
             const short* __restrict__ ftH, const short* __restrict__ ftL,
             float* __restrict__ out)
{
    __shared__ short wSH[4][MT][AFP];           // 18 KB  w hi  [h][m][k]
    __shared__ short wSL[4][MT][AFP];           // 18 KB  w lo
    __shared__ short affS[2][2][MT][AFP];       // 18 KB  [hi/lo][hl][m][nn]
    __shared__ float msS[NRANGE];               //  4 KB
    __shared__ float bS[4][MT];                 //  1 KB

    // bijective XCD swizzle: all 64 blocks of one nc land on one XCD
    const int bid  = blockIdx.x;
    const int wid  = (bid & 7) * 64 + (bid >> 3);
    const int nc   = wid >> 6;
    const int rest = wid & 63;
    const int mt0  = rest & 15;
    const int hp   = (rest >> 4) & 1;           // head-pair this block outputs
    const int b    = rest >> 5;
    const int m0   = mt0 * MT;
    const int n0   = nc * NRANGE;

    const int t  = threadIdx.x;
    const int wv = t >> 6, l = t & 63, lr = l & 15, lg = l >> 4;
    // sim roles: wave = (n-tile, m-quad)
    const int nt = wv & 1, mq = wv >> 1;
    // readout roles: wave = (local head, cv-half, m-half)
    const int hl = wv & 1, cvh = (wv >> 1) & 1, mh = (wv >> 2) & 1;

    // ---- setup: ms staging + per-(h,m) weights/bias ----
    if (t < 256) {
        ((f4*)msS)[t] = ((const f4*)(ms + (size_t)b * THW + n0))[t];
        const int h = t >> 6, m = t & 63;
        const float* qkp = qk + (size_t)(b * 64 + h * 16) * HWD + m0 + m;
        const float* qep = qe + (size_t)(b * 64 + h * 16) * HWD + m0 + m;
        float bias = 0.f;
#pragma unroll
        for (int c = 0; c < 16; ++c) {
            float kv = qkp[(size_t)c * HWD];
            float ev = qep[(size_t)c * HWD];
            float w0 = -ev, w1 = 2.f * kv * ev;
            unsigned short h0 = f2bf(w0), h1w = f2bf(w1);
            unsigned short l0 = f2bf(w0 - bf2f(h0)), l1 = f2bf(w1 - bf2f(h1w));
            *(unsigned*)&wSH[h][m][2 * c] = (unsigned)h0 | ((unsigned)h1w << 16);
            *(unsigned*)&wSL[h][m][2 * c] = (unsigned)l0 | ((unsigned)l1 << 16);
            bias -= ev * kv * kv * kv;
        }
        bS[h][m] = bias;
    }
    __syncthreads();

    float biasr[4];
#pragma unroll
    for (int h = 0; h < 4; ++h) biasr[h] = bS[h][mq * 16 + lr];

    f4 acc[4][2];
#pragma unroll
    for (int ct = 0; ct < 4; ++ct) {
        acc[ct][0] = f4{0.f, 0.f, 0.f, 0.f};
        acc[ct][1] = f4{0.f, 0.f, 0.f, 0.f};
    }

    for (int s = 0; s < SUBS; ++s) {
        const int ns = s * NSUB;

        // ===== sim: per-head MFMA, softmax fully in-register =====
        f4 sacc[4];
        {
            const int nrow = n0 + ns + nt * 16 + lr;
#pragma unroll
            for (int h = 0; h < 4; ++h) {
                size_t fo = ((size_t)(b * 4 + h) * THW + nrow) * 32 + lg * 8;
                s8 fH = *(const s8*)(ftH + fo);
                s8 fL = *(const s8*)(ftL + fo);
                const short* wrH = &wSH[h][mq * 16 + lr][lg * 8];
                const short* wrL = &wSL[h][mq * 16 + lr][lg * 8];
                s8 wH = __builtin_shufflevector(*(const s4*)wrH, *(const s4*)(wrH + 4), 0,1,2,3,4,5,6,7);
                s8 wL = __builtin_shufflevector(*(const s4*)wrL, *(const s4*)(wrL + 4), 0,1,2,3,4,5,6,7);
                f4 sa = f4{0.f, 0.f, 0.f, 0.f};
                sa = MFMA16(fH, wH, sa, 0, 0, 0);
                sa = MFMA16(fL, wH, sa, 0, 0, 0);
                sa = MFMA16(fH, wL, sa, 0, 0, 0);
                sacc[h] = sa;
            }
        }
        // issue readout A-loads early (latency hidden under softmax + barrier)
        s8 aHr[4], aLr[4];
#pragma unroll
        for (int ct = 0; ct < 4; ++ct) {
            size_t ao = ((size_t)(b * CVD + hp * 256 + hl * 128 + cvh * 64 + ct * 16 + lr)) * THW
                        + n0 + ns + lg * 8;
            aHr[ct] = *(const s8*)(mvH + ao);
            aLr[ct] = *(const s8*)(mvL + ao);
        }
        // softmax over heads (in-lane) + bf16 hi/lo aff into B-fragment layout
        {
            f4 msv = *(const f4*)&msS[ns + nt * 16 + lg * 4];
            short hi0[4], hi1[4], lo0[4], lo1[4];
#pragma unroll
            for (int r = 0; r < 4; ++r) {
                float x[4];
#pragma unroll
                for (int h = 0; h < 4; ++h)
                    x[h] = (sacc[h][r] + biasr[h]) * msv[r] * 0.125f;
                float mx = fmaxf(fmaxf(x[0], x[1]), fmaxf(x[2], x[3]));
                float e0 = __expf(x[0] - mx), e1 = __expf(x[1] - mx);
                float e2 = __expf(x[2] - mx), e3 = __expf(x[3] - mx);
                float rin = 1.f / (e0 + e1 + e2 + e3);
                float a0 = (hp ? e2 : e0) * rin;
                float a1 = (hp ? e3 : e1) * rin;
                unsigned short hA = f2bf(a0), hB = f2bf(a1);
                hi0[r] = (short)hA; lo0[r] = (short)f2bf(a0 - bf2f(hA));
                hi1[r] = (short)hB; lo1[r] = (short)f2bf(a1 - bf2f(hB));
            }
            const int mrow = mq * 16 + lr, nn = nt * 16 + lg * 4;
            *(s4*)&affS[0][0][mrow][nn] = s4{hi0[0], hi0[1], hi0[2], hi0[3]};
            *(s4*)&affS[1][0][mrow][nn] = s4{lo0[0], lo0[1], lo0[2], lo0[3]};
            *(s4*)&affS[0][1][mrow][nn] = s4{hi1[0], hi1[1], hi1[2], hi1[3]};
            *(s4*)&affS[1][1][mrow][nn] = s4{lo1[0], lo1[1], lo1[2], lo1[3]};
        }
        __syncthreads();

        // ===== readout: 3-product hi/lo MFMA =====
        {
            s8 bH[2], bL[2];
#pragma unroll
            for (int mt = 0; mt < 2; ++mt) {
                const short* pH = &affS[0][hl][mh * 32 + mt * 16 + lr][lg * 8];
                const short* pL = &affS[1][hl][mh * 32 + mt * 16 + lr][lg * 8];
                bH[mt] = __builtin_shufflevector(*(const s4*)pH, *(const s4*)(pH + 4), 0,1,2,3,4,5,6,7);
                bL[mt] = __builtin_shufflevector(*(const s4*)pL, *(const s4*)(pL + 4), 0,1,2,3,4,5,6,7);
            }
#pragma unroll
            for (int ct = 0; ct < 4; ++ct)
#pragma unroll
                for (int mt = 0; mt < 2; ++mt) {
                    acc[ct][mt] = MFMA16(aHr[ct], bH[mt], acc[ct][mt], 0, 0, 0);
                    acc[ct][mt] = MFMA16(aLr[ct], bH[mt], acc[ct][mt], 0, 0, 0);
                    acc[ct][mt] = MFMA16(aHr[ct], bL[mt], acc[ct][mt], 0, 0, 0);
                }
        }
        __syncthreads();
    }

    // ---- epilogue: combine n-chunk partials via hw fp32 atomics ----
    float* ob = out + (size_t)b * (2 * CVD * HWD);
#pragma unroll
    for (int ct = 0; ct < 4; ++ct)
#pragma unroll
        for (int mt = 0; mt < 2; ++mt)
#pragma unroll
            for (int r = 0; r < 4; ++r) {
                const int cv = hp * 256 + hl * 128 + cvh * 64 + ct * 16 + lg * 4 + r;
                const int m  = m0 + mh * 32 + mt * 16 + lr;
#if defined(__HIP_PLATFORM_AMD__)
                unsafeAtomicAdd(ob + (size_t)cv * HWD + m, acc[ct][mt][r]);
#else
                atomicAdd(ob + (size_t)cv * HWD + m, acc[ct][mt][r]);
#endif
            }
}

extern "C" void kernel_launch(void* const* d_in, const int* in_sizes, int n_in,
                              void* d_out, int out_size, void* d_ws, size_t ws_size,
                              hipStream_t stream) {
    (void)in_sizes; (void)n_in; (void)out_size; (void)ws_size;
    const float* mk = (const float*)d_in[0];
    const float* qk = (const float*)d_in[1];
    const float* ms = (const float*)d_in[2];
    const float* qe = (const float*)d_in[3];
    const float* mv = (const float*)d_in[4];
    const float* qv = (const float*)d_in[5];
    float* out = (float*)d_out;

    // ws layout: mvH 16MiB | mvL 16MiB | ftH 4MiB | ftL 4MiB  (total 40 MiB)
    short* mvH = (short*)d_ws;
    short* mvL = (short*)((char*)d_ws + 16777216);
    short* ftH = (short*)((char*)d_ws + 33554432);
    short* ftL = (short*)((char*)d_ws + 37748736);

    mr_init<<<2048, 256, 0, stream>>>(qv, out);
    prep_mv<<<8192, 256, 0, stream>>>(mv, mvH, mvL);
    prep_feat<<<256, 256, 0, stream>>>(mk, ftH, ftL);
    mr_main<<<512, 512, 0, stream>>>(qk, qe, ms, mvH, mvL, ftH, ftL, out);
}